// Round 8
// baseline (318.290 us; speedup 1.0000x reference)
//
#include <hip/hip_runtime.h>
#include <hip/hip_bf16.h>

typedef short bf16x8 __attribute__((ext_vector_type(8)));
typedef short bf16x4 __attribute__((ext_vector_type(4)));
typedef float f32x4  __attribute__((ext_vector_type(4)));

static constexpr int Bb   = 128;
static constexpr int Cin  = 32;
static constexpr int Nn   = 325;
static constexpr int Tt   = 24;
static constexpr int Cout = 64;
static constexpr int NKS  = 11;    // K steps (352 = 11*32)
static constexpr int WP   = 336;   // padded w rows in stpb
static constexpr int NWT  = 21;
static constexpr size_t XTB_ELEMS = (size_t)Bb * NKS * (Tt * Cin) * 32;
static constexpr size_t STP_ELEMS = (size_t)4 * NKS * WP * 32;
static constexpr size_t WB_ELEMS  = (size_t)Cout * 128;

__device__ __forceinline__ void gld16(const void* g, void* l) {
    __builtin_amdgcn_global_load_lds(
        (const __attribute__((address_space(1))) void*)g,
        (__attribute__((address_space(3))) void*)l, 16, 0, 0);
}
__device__ __forceinline__ short bfb(float f) {
    __hip_bfloat16 h = __float2bfloat16(f);
    return *reinterpret_cast<short*>(&h);
}

// ---------- P1: stpb[e][ks][w(336)][vi(32)] bf16, identity-augmented ------
__global__ void build_stp(const float* __restrict__ sup,
                          __hip_bfloat16* __restrict__ stpb) {
    int idx = blockIdx.x * 256 + threadIdx.x;
    int total = 4 * NKS * WP * 32;
    if (idx >= total) return;
    int e  = idx / (NKS * WP * 32);
    int r  = idx % (NKS * WP * 32);
    int ks = r / (WP * 32);
    int r2 = r % (WP * 32);
    int w  = r2 / 32;
    int vi = r2 % 32;
    int v  = ks * 32 + vi;
    float val = 0.f;
    if (e == 0) {
        val = (v == w && v < Nn) ? 1.f : 0.f;
    } else if (v < Nn && w < Nn) {
        val = sup[((size_t)(e - 1) * Nn + v) * Nn + w];
    }
    stpb[idx] = __float2bfloat16(val);
}

// ---------- P1b: W fp32 -> bf16 [64][128] ---------------------------------
__global__ void build_wb(const float* __restrict__ W,
                         __hip_bfloat16* __restrict__ Wb) {
    int i = blockIdx.x * 256 + threadIdx.x;
    if (i < Cout * 128) Wb[i] = __float2bfloat16(W[i]);
}

// ---------- P2: x -> xTb[b][ks][ct=t*32+c][vi(32)]; XCD-affine: b/16 ------
__global__ void transpose_x(const float* __restrict__ x,
                            __hip_bfloat16* __restrict__ xTb) {
    __shared__ __hip_bfloat16 ls[Cin * 32 * 28];   // [c][vi][28] 57344 B
    // map so XCD (bid&7) writes b in [xcd*16, xcd*16+16) -> main kernel's
    // readers of the same b live on the same XCD -> local-L2-warm first touch
    int xcd = blockIdx.x & 7;
    int idx = blockIdx.x >> 3;        // [0,176): 16 b x 11 ks
    int b   = xcd * 16 + idx / NKS;
    int ks  = idx % NKS;
    int tid = threadIdx.x;
    for (int i = 0; i < 24; ++i) {
        int f4 = i * 256 + tid;
        int c  = f4 / 192;
        int rm = f4 % 192;
        int vi = rm / 6;
        int t0 = (rm % 6) * 4;
        int v  = ks * 32 + vi;
        float4 val = make_float4(0.f, 0.f, 0.f, 0.f);
        if (v < Nn)
            val = *(const float4*)(x + (((size_t)(b * Cin + c) * Nn + v) * Tt + t0));
        bf16x4 pk = { bfb(val.x), bfb(val.y), bfb(val.z), bfb(val.w) };
        *(bf16x4*)&ls[(c * 32 + vi) * 28 + t0] = pk;
    }
    __syncthreads();
    for (int j = 0; j < 12; ++j) {
        int o    = j * 256 + tid;
        int row  = o >> 2;
        int slot = o & 3;
        int t = row >> 5, c = row & 31;
        union { short us[8]; bf16x8 v8; } pk;
#pragma unroll
        for (int q = 0; q < 8; ++q) {
            __hip_bfloat16 h = ls[(c * 32 + slot * 8 + q) * 28 + t];
            pk.us[q] = *reinterpret_cast<short*>(&h);
        }
        *(bf16x8*)((char*)xTb + ((size_t)(b * NKS + ks) * 768 + row) * 64 + slot * 16) = pk.v8;
    }
}

// ---------- M: block=(b,wt), 8 waves; rotated K-sweep; conflict-free Ss ---
__global__ __launch_bounds__(512, 2) void graphconv_main(
    const __hip_bfloat16* __restrict__ xTb,
    const __hip_bfloat16* __restrict__ stpb,
    const __hip_bfloat16* __restrict__ Wb,
    const float* __restrict__ bias,
    float* __restrict__ out) {
    __shared__ alignas(16) __hip_bfloat16 Ss[44 * 512];   // 45056 B (S' all-K)
    __shared__ float Os[16 * 401];                        // 25664 B (epilogue)

    // bijective XCD swizzle: 2688 = 8 * 336; wt innermost (X L2 reuse x21)
    int bid = blockIdx.x;
    int lg  = (bid & 7) * 336 + (bid >> 3);
    int b   = lg / NWT;
    int wt  = lg % NWT;
    int w0  = wt * 16;

    int tid = threadIdx.x, wid = tid >> 6, lane = tid & 63;
    int cl = lane & 15, kg = lane >> 4;

    const char* xslab = (const char*)xTb + (size_t)b * NKS * 768 * 64;
    const char* xbase = xslab + (size_t)(wid * 96 + cl) * 64 + kg * 16;

    // K-phase rotation: decorrelate the 21 same-b blocks' cold misses
    int rot = lg % NKS;

    // ---- stage S' once: Ss[i=(e*11+ks)][w(16)][32v]; R5 conflict-free ----
    {
        int srow  = lane >> 2;                           // row 0..15
        int sslot = ((lane & 3) ^ ((lane >> 3) & 3)) << 4; // q ^ ((row>>1)&3)
        for (int i = wid; i < 44; i += 8) {
            int e = i / NKS, ks = i % NKS;
            gld16((const char*)stpb +
                      ((size_t)((e * NKS + ks) * WP) + w0 + srow) * 64 + sslot,
                  (char*)&Ss[0] + i * 1024 + lane * 16);
        }
    }

    // ---- xf prologue: first two rotated K-steps ----
    int ks0 = rot;
    int ks1 = (rot + 1 == NKS) ? 0 : rot + 1;
    bf16x8 xf[3][6];
#pragma unroll
    for (int j = 0; j < 6; ++j) {
        xf[0][j] = *(const bf16x8*)(xbase + (size_t)ks0 * 49152 + (size_t)j * 1024);
        xf[1][j] = *(const bf16x8*)(xbase + (size_t)ks1 * 49152 + (size_t)j * 1024);
    }

    __syncthreads();   // Ss resident

    const int asw = (kg ^ ((cl >> 1) & 3)) << 4;   // read-side slot swizzle
    bf16x8 af[2][4];
#pragma unroll
    for (int e = 0; e < 4; ++e)
        af[0][e] = *(const bf16x8*)((const char*)&Ss[0] +
                                    (size_t)(e * NKS + ks0) * 1024 + cl * 64 + asw);

    // ---- GEMM1: rotated sweep; 2-ahead global, 1-ahead LDS prefetch ----
    f32x4 acc1[4][6] = {};
    int ksp = (rot + 2 >= NKS) ? rot + 2 - NKS : rot + 2;  // kk+2 phase
    int ksn = ks1;                                          // kk+1 phase
#pragma unroll
    for (int kk = 0; kk < NKS; ++kk) {
        const int cur3 = kk % 3, pf3 = (kk + 2) % 3;
        const int cur2 = kk & 1, nx2 = cur2 ^ 1;
        if (kk + 2 < NKS) {
#pragma unroll
            for (int j = 0; j < 6; ++j)
                xf[pf3][j] = *(const bf16x8*)(xbase + (size_t)ksp * 49152 +
                                              (size_t)j * 1024);
        }
        if (kk + 1 < NKS) {
#pragma unroll
            for (int e = 0; e < 4; ++e)
                af[nx2][e] = *(const bf16x8*)((const char*)&Ss[0] +
                                 (size_t)(e * NKS + ksn) * 1024 + cl * 64 + asw);
        }
        __builtin_amdgcn_s_setprio(1);
#pragma unroll
        for (int e = 0; e < 4; ++e)
#pragma unroll
            for (int j = 0; j < 6; ++j)
                acc1[e][j] = __builtin_amdgcn_mfma_f32_16x16x32_bf16(
                    xf[cur3][j], af[cur2][e], acc1[e][j], 0, 0, 0);
        __builtin_amdgcn_s_setprio(0);
        ksp = (ksp + 1 == NKS) ? 0 : ksp + 1;
        ksn = (ksn + 1 == NKS) ? 0 : ksn + 1;
    }

    // ---- GEMM2 from registers: kappa = e*2 + (j&1), tj = j>>1 ----
    f32x4 acc2[4][3] = {};
#pragma unroll
    for (int kappa = 0; kappa < 8; ++kappa) {
        const int e = kappa >> 1, half = kappa & 1;
        bf16x4 wf[4];
#pragma unroll
        for (int mt = 0; mt < 4; ++mt)
            wf[mt] = *(const bf16x4*)((const char*)Wb + (mt * 16 + cl) * 256 +
                                      kappa * 32 + kg * 8);
#pragma unroll
        for (int tj = 0; tj < 3; ++tj) {
            const int j = tj * 2 + half;
            f32x4 y = acc1[e][j];
            bf16x4 pb = { bfb(y[0]), bfb(y[1]), bfb(y[2]), bfb(y[3]) };
#pragma unroll
            for (int mt = 0; mt < 4; ++mt)
                acc2[mt][tj] = __builtin_amdgcn_mfma_f32_16x16x16bf16_1k(
                    wf[mt], pb, acc2[mt][tj], 0, 0, 0);
        }
    }

    // ---- epilogue: 4 passes of 16 o; LDS transpose; full-line stores -----
#pragma unroll
    for (int p = 0; p < 4; ++p) {
        if (p) __syncthreads();            // previous pass reads done
#pragma unroll
        for (int tj = 0; tj < 3; ++tj) {
            const int t = wid * 3 + tj;
#pragma unroll
            for (int r = 0; r < 4; ++r)
                Os[(kg * 4 + r) * 401 + cl * 25 + t] = acc2[p][tj][r];
        }
        __syncthreads();
        const int o2 = tid >> 5, th_ = (tid >> 4) & 1, w = tid & 15;
        const int wg = w0 + w;
        if (wg < Nn) {
            const int o = p * 16 + o2;
            const float bv = bias[o];
            float f[12];
#pragma unroll
            for (int q = 0; q < 12; ++q)
                f[q] = Os[o2 * 401 + w * 25 + th_ * 12 + q] + bv;
            float* op = out + ((size_t)(b * Cout + o) * Nn + wg) * Tt + th_ * 12;
#pragma unroll
            for (int q = 0; q < 3; ++q)
                *(float4*)(op + q * 4) =
                    make_float4(f[q * 4], f[q * 4 + 1], f[q * 4 + 2], f[q * 4 + 3]);
        }
    }
}

extern "C" void kernel_launch(void* const* d_in, const int* in_sizes, int n_in,
                              void* d_out, int out_size, void* d_ws, size_t ws_size,
                              hipStream_t stream) {
    const float* x    = (const float*)d_in[0];
    const float* sup  = (const float*)d_in[1];
    const float* W    = (const float*)d_in[2];
    const float* bias = (const float*)d_in[3];
    float* out = (float*)d_out;

    __hip_bfloat16* xTb  = (__hip_bfloat16*)d_ws;
    __hip_bfloat16* stpb = xTb + XTB_ELEMS;
    __hip_bfloat16* Wb   = stpb + STP_ELEMS;

    build_stp<<<(int)((STP_ELEMS + 255) / 256), 256, 0, stream>>>(sup, stpb);
    build_wb<<<(int)((WB_ELEMS + 255) / 256), 256, 0, stream>>>(W, Wb);
    transpose_x<<<Bb * NKS, 256, 0, stream>>>(x, xTb);
    graphconv_main<<<Bb * NWT, 512, 0, stream>>>(xTb, stpb, Wb, bias, out);
}

// Round 9
// 308.955 us; speedup vs baseline: 1.0302x; 1.0302x over previous
//
#include <hip/hip_runtime.h>
#include <hip/hip_bf16.h>

typedef short bf16x8 __attribute__((ext_vector_type(8)));
typedef short bf16x4 __attribute__((ext_vector_type(4)));
typedef float f32x4  __attribute__((ext_vector_type(4)));

static constexpr int Bb   = 128;
static constexpr int Cin  = 32;
static constexpr int Nn   = 325;
static constexpr int Tt   = 24;
static constexpr int Cout = 64;
static constexpr int NKS  = 11;    // K steps (352 = 11*32)
static constexpr int WP   = 336;   // padded w rows in stpb
static constexpr int NWT  = 21;
static constexpr int OS1  = 210;   // Os o-stride (mod 8 == 2 -> 2-way max)
static constexpr size_t XTB_ELEMS = (size_t)Bb * NKS * (Tt * Cin) * 32;
static constexpr size_t STP_ELEMS = (size_t)4 * NKS * WP * 32;
static constexpr size_t WB_ELEMS  = (size_t)Cout * 128;

__device__ __forceinline__ void gld16(const void* g, void* l) {
    __builtin_amdgcn_global_load_lds(
        (const __attribute__((address_space(1))) void*)g,
        (__attribute__((address_space(3))) void*)l, 16, 0, 0);
}
__device__ __forceinline__ short bfb(float f) {
    __hip_bfloat16 h = __float2bfloat16(f);
    return *reinterpret_cast<short*>(&h);
}

// ---------- P1: stpb[e][ks][w(336)][vi(32)] bf16, identity-augmented ------
__global__ void build_stp(const float* __restrict__ sup,
                          __hip_bfloat16* __restrict__ stpb) {
    int idx = blockIdx.x * 256 + threadIdx.x;
    int total = 4 * NKS * WP * 32;
    if (idx >= total) return;
    int e  = idx / (NKS * WP * 32);
    int r  = idx % (NKS * WP * 32);
    int ks = r / (WP * 32);
    int r2 = r % (WP * 32);
    int w  = r2 / 32;
    int vi = r2 % 32;
    int v  = ks * 32 + vi;
    float val = 0.f;
    if (e == 0) {
        val = (v == w && v < Nn) ? 1.f : 0.f;
    } else if (v < Nn && w < Nn) {
        val = sup[((size_t)(e - 1) * Nn + v) * Nn + w];
    }
    stpb[idx] = __float2bfloat16(val);
}

// ---------- P1b: W fp32 -> bf16 [64][128] ---------------------------------
__global__ void build_wb(const float* __restrict__ W,
                         __hip_bfloat16* __restrict__ Wb) {
    int i = blockIdx.x * 256 + threadIdx.x;
    if (i < Cout * 128) Wb[i] = __float2bfloat16(W[i]);
}

// ---------- P2: x -> xTb[b][ks][ct=t*32+c][vi(32)]; XCD-affine: b/16 ------
__global__ void transpose_x(const float* __restrict__ x,
                            __hip_bfloat16* __restrict__ xTb) {
    __shared__ __hip_bfloat16 ls[Cin * 32 * 28];   // [c][vi][28] 57344 B
    int xcd = blockIdx.x & 7;
    int idx = blockIdx.x >> 3;        // [0,176): 16 b x 11 ks
    int b   = xcd * 16 + idx / NKS;
    int ks  = idx % NKS;
    int tid = threadIdx.x;
    for (int i = 0; i < 24; ++i) {
        int f4 = i * 256 + tid;
        int c  = f4 / 192;
        int rm = f4 % 192;
        int vi = rm / 6;
        int t0 = (rm % 6) * 4;
        int v  = ks * 32 + vi;
        float4 val = make_float4(0.f, 0.f, 0.f, 0.f);
        if (v < Nn)
            val = *(const float4*)(x + (((size_t)(b * Cin + c) * Nn + v) * Tt + t0));
        bf16x4 pk = { bfb(val.x), bfb(val.y), bfb(val.z), bfb(val.w) };
        *(bf16x4*)&ls[(c * 32 + vi) * 28 + t0] = pk;
    }
    __syncthreads();
    for (int j = 0; j < 12; ++j) {
        int o    = j * 256 + tid;
        int row  = o >> 2;
        int slot = o & 3;
        int t = row >> 5, c = row & 31;
        union { short us[8]; bf16x8 v8; } pk;
#pragma unroll
        for (int q = 0; q < 8; ++q) {
            __hip_bfloat16 h = ls[(c * 32 + slot * 8 + q) * 28 + t];
            pk.us[q] = *reinterpret_cast<short*>(&h);
        }
        *(bf16x8*)((char*)xTb + ((size_t)(b * NKS + ks) * 768 + row) * 64 + slot * 16) = pk.v8;
    }
}

// ---------- M: block=(b,wt,th) 256thr/4waves -> 2 de-phased blocks/CU -----
__global__ __launch_bounds__(256, 2) void graphconv_main(
    const __hip_bfloat16* __restrict__ xTb,
    const __hip_bfloat16* __restrict__ stpb,
    const __hip_bfloat16* __restrict__ Wb,
    const float* __restrict__ bias,
    float* __restrict__ out) {
    __shared__ alignas(16) __hip_bfloat16 Ss[44 * 512];   // 45056 B (S' all-K)
    __shared__ float Os[16 * OS1];                        // 13440 B (epilogue)

    // bijective XCD swizzle: 5376 = 8 * 672; th innermost, wt next (X reuse)
    int bid = blockIdx.x;
    int lg  = (bid & 7) * 672 + (bid >> 3);
    int b   = lg / 42;
    int r   = lg % 42;
    int wt  = r >> 1, th = r & 1;
    int w0  = wt * 16;

    int tid = threadIdx.x, wid = tid >> 6, lane = tid & 63;
    int cl = lane & 15, kg = lane >> 4;

    const char* xslab = (const char*)xTb + (size_t)b * NKS * 768 * 64;
    const char* xbase = xslab + (size_t)(th * 384 + wid * 96 + cl) * 64 + kg * 16;

    // ---- stage S' once: Ss[i=(e*11+ks)][w(16)][32v]; R5 conflict-free ----
    {
        int srow  = lane >> 2;                             // row 0..15
        int sslot = ((lane & 3) ^ ((lane >> 3) & 3)) << 4; // q ^ ((row>>1)&3)
        for (int i = wid; i < 44; i += 4) {
            int e = i / NKS, ks = i % NKS;
            gld16((const char*)stpb +
                      ((size_t)((e * NKS + ks) * WP) + w0 + srow) * 64 + sslot,
                  (char*)&Ss[0] + i * 1024 + lane * 16);
        }
    }

    // ---- xf prologue: ks = 0,1 ----
    bf16x8 xf[3][6];
#pragma unroll
    for (int s = 0; s < 2; ++s)
#pragma unroll
        for (int j = 0; j < 6; ++j)
            xf[s][j] = *(const bf16x8*)(xbase + (size_t)s * 49152 + (size_t)j * 1024);

    __syncthreads();   // Ss resident

    const int asw = (kg ^ ((cl >> 1) & 3)) << 4;   // read-side slot swizzle
    bf16x8 af[2][4];
#pragma unroll
    for (int e = 0; e < 4; ++e)
        af[0][e] = *(const bf16x8*)((const char*)&Ss[0] +
                                    (size_t)(e * NKS) * 1024 + cl * 64 + asw);

    // ---- GEMM1: Y^T[ct][w]; 2-ahead global, 1-ahead LDS prefetch ----
    f32x4 acc1[4][6] = {};
#pragma unroll
    for (int ks = 0; ks < NKS; ++ks) {
        const int cur3 = ks % 3, pf3 = (ks + 2) % 3;
        const int cur2 = ks & 1, nx2 = cur2 ^ 1;
        if (ks + 2 < NKS) {
#pragma unroll
            for (int j = 0; j < 6; ++j)
                xf[pf3][j] = *(const bf16x8*)(xbase + (size_t)(ks + 2) * 49152 +
                                              (size_t)j * 1024);
        }
        if (ks + 1 < NKS) {
#pragma unroll
            for (int e = 0; e < 4; ++e)
                af[nx2][e] = *(const bf16x8*)((const char*)&Ss[0] +
                                 (size_t)(e * NKS + ks + 1) * 1024 + cl * 64 + asw);
        }
        __builtin_amdgcn_s_setprio(1);
#pragma unroll
        for (int e = 0; e < 4; ++e)
#pragma unroll
            for (int j = 0; j < 6; ++j)
                acc1[e][j] = __builtin_amdgcn_mfma_f32_16x16x32_bf16(
                    xf[cur3][j], af[cur2][e], acc1[e][j], 0, 0, 0);
        __builtin_amdgcn_s_setprio(0);
    }

    // ---- GEMM2 from registers: kappa = e*2 + (j&1), tj = j>>1 ----
    // lane holds Y^T[ct = th*384 + wid*96 + j*16 + kg*4 + r][w = w0+cl]:
    //   t = th*12 + wid*3 + (j>>1), c = (j&1)*16 + kg*4 + r => B-frag k=kg*4+i
    f32x4 acc2[4][3] = {};
#pragma unroll
    for (int kappa = 0; kappa < 8; ++kappa) {
        const int e = kappa >> 1, half = kappa & 1;
        bf16x4 wf[4];
#pragma unroll
        for (int mt = 0; mt < 4; ++mt)
            wf[mt] = *(const bf16x4*)((const char*)Wb + (mt * 16 + cl) * 256 +
                                      kappa * 32 + kg * 8);
#pragma unroll
        for (int tj = 0; tj < 3; ++tj) {
            const int j = tj * 2 + half;
            f32x4 y = acc1[e][j];
            bf16x4 pb = { bfb(y[0]), bfb(y[1]), bfb(y[2]), bfb(y[3]) };
#pragma unroll
            for (int mt = 0; mt < 4; ++mt)
                acc2[mt][tj] = __builtin_amdgcn_mfma_f32_16x16x16bf16_1k(
                    wf[mt], pb, acc2[mt][tj], 0, 0, 0);
        }
    }

    // ---- epilogue: 4 passes of 16 o; Os[o2*210 + w*13 + t], 12 t ----
#pragma unroll
    for (int p = 0; p < 4; ++p) {
        if (p) __syncthreads();            // previous pass reads done
#pragma unroll
        for (int tj = 0; tj < 3; ++tj) {
            const int t = wid * 3 + tj;
#pragma unroll
            for (int r2_ = 0; r2_ < 4; ++r2_)
                Os[(kg * 4 + r2_) * OS1 + cl * 13 + t] = acc2[p][tj][r2_];
        }
        __syncthreads();
        const int o2 = tid >> 4, w = tid & 15;
        const int wg = w0 + w;
        if (wg < Nn) {
            const int o = p * 16 + o2;
            const float bv = bias[o];
            float f[12];
#pragma unroll
            for (int q = 0; q < 12; ++q)
                f[q] = Os[o2 * OS1 + w * 13 + q] + bv;
            float* op = out + ((size_t)(b * Cout + o) * Nn + wg) * Tt + th * 12;
#pragma unroll
            for (int q = 0; q < 3; ++q)
                *(float4*)(op + q * 4) =
                    make_float4(f[q * 4], f[q * 4 + 1], f[q * 4 + 2], f[q * 4 + 3]);
        }
    }
}

extern "C" void kernel_launch(void* const* d_in, const int* in_sizes, int n_in,
                              void* d_out, int out_size, void* d_ws, size_t ws_size,
                              hipStream_t stream) {
    const float* x    = (const float*)d_in[0];
    const float* sup  = (const float*)d_in[1];
    const float* W    = (const float*)d_in[2];
    const float* bias = (const float*)d_in[3];
    float* out = (float*)d_out;

    __hip_bfloat16* xTb  = (__hip_bfloat16*)d_ws;
    __hip_bfloat16* stpb = xTb + XTB_ELEMS;
    __hip_bfloat16* Wb   = stpb + STP_ELEMS;

    build_stp<<<(int)((STP_ELEMS + 255) / 256), 256, 0, stream>>>(sup, stpb);
    build_wb<<<(int)((WB_ELEMS + 255) / 256), 256, 0, stream>>>(W, Wb);
    transpose_x<<<Bb * NKS, 256, 0, stream>>>(x, xTb);
    graphconv_main<<<Bb * NWT * 2, 256, 0, stream>>>(xTb, stpb, Wb, bias, out);
}